// Round 5
// baseline (849.616 us; speedup 1.0000x reference)
//
#include <hip/hip_runtime.h>

#define N_NODES   100000
#define N_EDGES   3200000
#define N_FEAT    128
#define HIDDEN    16
#define MLP_H     100
#define N_CLASSES 12
#define N_GRAPHS  512
#define NBLK      391            // ceil(N_NODES/256)
#define BNODES    256            // nodes per bucket (dst>>8)
#define NBUCK     391            // ceil(N_NODES/256)
#define CPAD      16             // counter padding (ints) -> 1 counter / 64B
#define RING      32             // LDS ring slots per bucket in kBin

// ---- bucket histogram (LDS-staged): bcnt[d>>8] += ... ---------------------
__global__ __launch_bounds__(256) void kBCnt(const int* __restrict__ dst,
                                             int* __restrict__ bcnt) {
    __shared__ int h[NBUCK];
    int t = threadIdx.x;
    for (int i = t; i < NBUCK; i += 256) h[i] = 0;
    __syncthreads();
    int nquad = N_EDGES / 4;
    for (int i = blockIdx.x * 256 + t; i < nquad; i += gridDim.x * 256) {
        int4 d4 = ((const int4*)dst)[i];
        atomicAdd(&h[d4.x >> 8], 1);
        atomicAdd(&h[d4.y >> 8], 1);
        atomicAdd(&h[d4.z >> 8], 1);
        atomicAdd(&h[d4.w >> 8], 1);
    }
    __syncthreads();
    for (int i = t; i < NBUCK; i += 256)
        if (h[i]) atomicAdd(&bcnt[i * CPAD], h[i]);
}

// ---- scan 16-aligned padded counts -> pb (bases), init gcursor ------------
__global__ __launch_bounds__(512) void kBScan(const int* __restrict__ bcnt,
                                              int* __restrict__ pb,
                                              int* __restrict__ gcursor) {
    __shared__ int sm[512];
    int t = threadIdx.x;
    int c  = (t < NBUCK) ? bcnt[t * CPAD] : 0;
    int ca = (c + 15) & ~15;
    sm[t] = ca;
    __syncthreads();
    for (int s = 1; s < 512; s <<= 1) {
        int a = (t >= s) ? sm[t - s] : 0;
        __syncthreads();
        sm[t] += a;
        __syncthreads();
    }
    if (t < NBUCK) {
        int p = sm[t] - ca;
        pb[t] = p;
        gcursor[t * CPAD] = p;
    }
}

// ---- LDS-staged binning: 64B single-writer chunk flushes ------------------
__global__ __launch_bounds__(512) void kBin(const int* __restrict__ src,
                                            const int* __restrict__ dst,
                                            int* __restrict__ gcursor,
                                            int* __restrict__ pairs) {
    __shared__ int ring[NBUCK * RING];   // 50048 B
    __shared__ int cnt[NBUCK];
    __shared__ int fl[NBUCK];
    int t = threadIdx.x;
    for (int i = t; i < NBUCK; i += 512) { cnt[i] = 0; fl[i] = 0; }
    __syncthreads();
    const int batch = 512 * 4;                       // 2048 edges per block-iter
    for (int base = blockIdx.x * batch; base < N_EDGES;
         base += gridDim.x * batch) {
        int e0 = base + t * 4;
        if (e0 < N_EDGES) {                          // N_EDGES % 4 == 0
            int4 d4 = *(const int4*)&dst[e0];
            int4 s4 = *(const int4*)&src[e0];
            int dd[4] = {d4.x, d4.y, d4.z, d4.w};
            int ss[4] = {s4.x, s4.y, s4.z, s4.w};
#pragma unroll
            for (int k = 0; k < 4; ++k) {
                int b = dd[k] >> 8;
                int p = atomicAdd(&cnt[b], 1);
                ring[b * RING + (p & (RING - 1))] = (ss[k] << 8) | (dd[k] & 255);
            }
        }
        __syncthreads();
        if (t < NBUCK) {
            while (cnt[t] - fl[t] >= 16) {
                int start = fl[t];
                int gpos = atomicAdd(&gcursor[t * CPAD], 16);
                int rbase = t * RING + (start & (RING - 1)); // 16-aligned, no wrap
                const int4* rp = (const int4*)&ring[rbase];
                int4* gp = (int4*)&pairs[gpos];              // gpos % 16 == 0 here
                gp[0] = rp[0]; gp[1] = rp[1]; gp[2] = rp[2]; gp[3] = rp[3];
                fl[t] = start + 16;
            }
        }
        __syncthreads();
    }
    if (t < NBUCK) {
        int pending = cnt[t] - fl[t];
        if (pending > 0) {
            int gpos = atomicAdd(&gcursor[t * CPAD], pending);
            for (int k = 0; k < pending; ++k)
                pairs[gpos + k] = ring[t * RING + ((fl[t] + k) & (RING - 1))];
        }
    }
}

// ---- per-bucket degree histogram -> dinv ----------------------------------
__global__ __launch_bounds__(256) void kDinvB(const int* __restrict__ pairs,
                                              const int* __restrict__ bcnt,
                                              const int* __restrict__ pb,
                                              float* __restrict__ dinv) {
    __shared__ int hist[BNODES];
    int b = blockIdx.x, t = threadIdx.x;
    hist[t] = 0;
    __syncthreads();
    int ecnt = bcnt[b * CPAD], pbeg = pb[b];
    for (int i = t; i < ecnt; i += 256)
        atomicAdd(&hist[pairs[pbeg + i] & 255], 1);
    __syncthreads();
    int g = b * BNODES + t;
    if (g < N_NODES) dinv[g] = rsqrtf((float)hist[t] + 1.0f);  // +1 = self loop
}

// ---------------- hp = (x @ W1) * dinv[n]  ---------------------------------
__global__ __launch_bounds__(256) void kGemm1(const float* __restrict__ x,
                                              const float* __restrict__ W1,
                                              const float* __restrict__ dinv,
                                              float* __restrict__ hp) {
    __shared__ float Ws[N_FEAT * HIDDEN];  // 8 KB
    for (int t = threadIdx.x; t < N_FEAT * HIDDEN; t += 256) Ws[t] = W1[t];
    __syncthreads();
    int n = blockIdx.x * 256 + threadIdx.x;
    if (n >= N_NODES) return;

    float acc[HIDDEN];
#pragma unroll
    for (int j = 0; j < HIDDEN; ++j) acc[j] = 0.f;

    const float4* xr = (const float4*)(x + (size_t)n * N_FEAT);
#pragma unroll 4
    for (int k4 = 0; k4 < N_FEAT / 4; ++k4) {
        float4 v = xr[k4];
        float xk[4] = {v.x, v.y, v.z, v.w};
#pragma unroll
        for (int kk = 0; kk < 4; ++kk) {
            const float4* wrow = (const float4*)&Ws[(k4 * 4 + kk) * HIDDEN];
#pragma unroll
            for (int j4 = 0; j4 < 4; ++j4) {
                float4 wv = wrow[j4];
                acc[j4 * 4 + 0] += xk[kk] * wv.x;
                acc[j4 * 4 + 1] += xk[kk] * wv.y;
                acc[j4 * 4 + 2] += xk[kk] * wv.z;
                acc[j4 * 4 + 3] += xk[kk] * wv.w;
            }
        }
    }
    float dv = dinv[n];
    float4* hr = (float4*)(hp + (size_t)n * HIDDEN);
#pragma unroll
    for (int j4 = 0; j4 < 4; ++j4)
        hr[j4] = make_float4(acc[j4 * 4 + 0] * dv, acc[j4 * 4 + 1] * dv,
                             acc[j4 * 4 + 2] * dv, acc[j4 * 4 + 3] * dv);
}

// ---- bucketed gather-aggregate into LDS tile ------------------------------
// agg[g] = dinv[g] * (hp[g] + sum_{(s,g) in E} hp[s])
__global__ __launch_bounds__(512) void kAggB(const float* __restrict__ hp,
                                             const float* __restrict__ dinv,
                                             const int* __restrict__ pairs,
                                             const int* __restrict__ bcnt,
                                             const int* __restrict__ pb,
                                             float* __restrict__ agg) {
    __shared__ float tile[BNODES * HIDDEN];  // 16 KB
    int b = blockIdx.x, t = threadIdx.x;
    for (int i = t; i < BNODES * HIDDEN; i += 512) tile[i] = 0.f;
    __syncthreads();
    int ecnt = bcnt[b * CPAD];
    int pbeg = pb[b];
    int g16 = t >> 4;          // group 0..31
    int j   = t & 15;          // feature
    const int STRIDE = 32 * 16;
    int cur = g16 * 16;
    int pv = (cur + j < ecnt) ? pairs[pbeg + cur + j] : -1;
    for (; cur < ecnt; cur += STRIDE) {
        int nx = cur + STRIDE;
        int pn = (nx + j < ecnt) ? pairs[pbeg + nx + j] : -1;  // prefetch
#pragma unroll
        for (int k = 0; k < 16; ++k) {
            int v = __shfl(pv, k, 16);
            if (v >= 0) {
                int d = v & 255;
                int s = v >> 8;
                atomicAdd(&tile[d * HIDDEN + j], hp[(size_t)s * HIDDEN + j]);
            }
        }
        pv = pn;
    }
    __syncthreads();
    int base = b * BNODES;
    for (int i = t; i < BNODES * HIDDEN; i += 512) {
        int n = i >> 4, jj = i & 15;
        int g = base + n;
        if (g < N_NODES)
            agg[(size_t)g * HIDDEN + jj] =
                (tile[i] + hp[(size_t)g * HIDDEN + jj]) * dinv[g];
    }
}

// ------- t = relu(agg1+b1); hp2 = (t @ W2) * dinv --------------------------
__global__ __launch_bounds__(256) void kLayer2(const float* __restrict__ agg1,
                                               const float* __restrict__ W2,
                                               const float* __restrict__ b1,
                                               const float* __restrict__ dinv,
                                               float* __restrict__ hp2) {
    __shared__ float Ws[HIDDEN * HIDDEN];
    __shared__ float bs[HIDDEN];
    if (threadIdx.x < HIDDEN * HIDDEN) Ws[threadIdx.x] = W2[threadIdx.x];
    if (threadIdx.x < HIDDEN) bs[threadIdx.x] = b1[threadIdx.x];
    __syncthreads();
    int n = blockIdx.x * 256 + threadIdx.x;
    if (n >= N_NODES) return;

    float t[HIDDEN];
    const float4* a1r = (const float4*)(agg1 + (size_t)n * HIDDEN);
#pragma unroll
    for (int j4 = 0; j4 < 4; ++j4) {
        float4 av = a1r[j4];
        t[j4 * 4 + 0] = fmaxf(av.x + bs[j4 * 4 + 0], 0.f);
        t[j4 * 4 + 1] = fmaxf(av.y + bs[j4 * 4 + 1], 0.f);
        t[j4 * 4 + 2] = fmaxf(av.z + bs[j4 * 4 + 2], 0.f);
        t[j4 * 4 + 3] = fmaxf(av.w + bs[j4 * 4 + 3], 0.f);
    }
    float acc[HIDDEN];
#pragma unroll
    for (int j = 0; j < HIDDEN; ++j) acc[j] = 0.f;
#pragma unroll
    for (int k = 0; k < HIDDEN; ++k) {
        const float4* wrow = (const float4*)&Ws[k * HIDDEN];
#pragma unroll
        for (int j4 = 0; j4 < 4; ++j4) {
            float4 wv = wrow[j4];
            acc[j4 * 4 + 0] += t[k] * wv.x;
            acc[j4 * 4 + 1] += t[k] * wv.y;
            acc[j4 * 4 + 2] += t[k] * wv.z;
            acc[j4 * 4 + 3] += t[k] * wv.w;
        }
    }
    float dv = dinv[n];
    float4* hr = (float4*)(hp2 + (size_t)n * HIDDEN);
#pragma unroll
    for (int j4 = 0; j4 < 4; ++j4)
        hr[j4] = make_float4(acc[j4 * 4 + 0] * dv, acc[j4 * 4 + 1] * dv,
                             acc[j4 * 4 + 2] * dv, acc[j4 * 4 + 3] * dv);
}

// ------- v = relu(agg2+b2); pooled[batch[n]] += v (block-reduced) ----------
__global__ __launch_bounds__(256) void kPool(const float* __restrict__ agg,
                                             const float* __restrict__ b2,
                                             const int* __restrict__ batch,
                                             float* __restrict__ pooled) {
    __shared__ float red[256];
    __shared__ int sseg[2];
    int t = threadIdx.x;
    int ln = t >> 4, j = t & 15;
    int n0 = blockIdx.x * 16;
    int n = n0 + ln;
    if (t == 0) sseg[0] = batch[n0];
    if (t == 1) sseg[1] = batch[min(n0 + 15, N_NODES - 1)];
    float v = 0.f;
    int bg = 0;
    bool valid = (n < N_NODES);
    if (valid) {
        bg = batch[n];
        v = fmaxf(agg[(size_t)n * HIDDEN + j] + b2[j], 0.f);
    }
    __syncthreads();
    if (sseg[0] == sseg[1]) {          // whole block in one graph (common)
        red[t] = v;
        __syncthreads();
        if (ln < 8) red[t] += red[t + 128];
        __syncthreads();
        if (ln < 4) red[t] += red[t + 64];
        __syncthreads();
        if (ln < 2) red[t] += red[t + 32];
        __syncthreads();
        if (ln == 0)
            unsafeAtomicAdd(&pooled[(size_t)sseg[0] * HIDDEN + j],
                            red[t] + red[t + 16]);
    } else {
        if (valid) unsafeAtomicAdd(&pooled[(size_t)bg * HIDDEN + j], v);
    }
}

// ------- g=relu(pooled); g1=relu(g@lw1+lb1); out=g1@lw2+lb2 ----------------
__global__ __launch_bounds__(64) void kMlp(const float* __restrict__ pooled,
                                           const float* __restrict__ lw1,
                                           const float* __restrict__ lb1,
                                           const float* __restrict__ lw2,
                                           const float* __restrict__ lb2,
                                           float* __restrict__ out) {
    int g = blockIdx.x * 64 + threadIdx.x;
    if (g >= N_GRAPHS) return;
    float gv[HIDDEN];
#pragma unroll
    for (int k = 0; k < HIDDEN; ++k)
        gv[k] = fmaxf(pooled[(size_t)g * HIDDEN + k], 0.f);
    float o[N_CLASSES];
#pragma unroll
    for (int c = 0; c < N_CLASSES; ++c) o[c] = lb2[c];
    for (int j = 0; j < MLP_H; ++j) {
        float s = lb1[j];
#pragma unroll
        for (int k = 0; k < HIDDEN; ++k) s += gv[k] * lw1[k * MLP_H + j];
        s = fmaxf(s, 0.f);
#pragma unroll
        for (int c = 0; c < N_CLASSES; ++c) o[c] += s * lw2[j * N_CLASSES + c];
    }
#pragma unroll
    for (int c = 0; c < N_CLASSES; ++c) out[(size_t)g * N_CLASSES + c] = o[c];
}

extern "C" void kernel_launch(void* const* d_in, const int* in_sizes, int n_in,
                              void* d_out, int out_size, void* d_ws,
                              size_t ws_size, hipStream_t stream) {
    const float* x     = (const float*)d_in[0];
    const int*   ei    = (const int*)d_in[1];
    const int*   batch = (const int*)d_in[2];
    const float* W1    = (const float*)d_in[3];
    const float* b1    = (const float*)d_in[4];
    const float* W2    = (const float*)d_in[5];
    const float* b2    = (const float*)d_in[6];
    const float* lw1   = (const float*)d_in[7];
    const float* lb1   = (const float*)d_in[8];
    const float* lw2   = (const float*)d_in[9];
    const float* lb2   = (const float*)d_in[10];
    float* out = (float*)d_out;

    const int* src = ei;
    const int* dst = ei + N_EDGES;

    // workspace layout (bytes)
    char* ws = (char*)d_ws;
    int*   bcnt    = (int*)(ws + 0);         // 391*64 = 25024 -> 25088
    int*   gcursor = (int*)(ws + 25088);     // 25024 -> 25088
    int*   pb      = (int*)(ws + 50176);     // 1564 -> 2048
    float* dinv    = (float*)(ws + 52224);   // 400000 -> 400384
    int*   pairs   = (int*)(ws + 452608);    // (3200000+391*16)*4 = 12825024
    float* hp      = (float*)(ws + 13277696);//  6400000
    float* agg     = (float*)(ws + 19677696);//  6400000
    float* pooled  = (float*)(ws + 26077696);//    32768  (end 26110464)

    hipMemsetAsync(bcnt, 0, NBUCK * CPAD * 4, stream);
    hipMemsetAsync(pooled, 0, 32768, stream);

    kBCnt<<<256, 256, 0, stream>>>(dst, bcnt);
    kBScan<<<1, 512, 0, stream>>>(bcnt, pb, gcursor);
    kBin<<<128, 512, 0, stream>>>(src, dst, gcursor, pairs);
    kDinvB<<<NBUCK, 256, 0, stream>>>(pairs, bcnt, pb, dinv);

    kGemm1<<<NBLK, 256, 0, stream>>>(x, W1, dinv, hp);
    kAggB<<<NBUCK, 512, 0, stream>>>(hp, dinv, pairs, bcnt, pb, agg);
    kLayer2<<<NBLK, 256, 0, stream>>>(agg, W2, b1, dinv, hp);
    kAggB<<<NBUCK, 512, 0, stream>>>(hp, dinv, pairs, bcnt, pb, agg);
    kPool<<<(N_NODES + 15) / 16, 256, 0, stream>>>(agg, b2, batch, pooled);
    kMlp<<<(N_GRAPHS + 63) / 64, 64, 0, stream>>>(pooled, lw1, lb1, lw2, lb2, out);
}

// Round 6
// 202.913 us; speedup vs baseline: 4.1871x; 4.1871x over previous
//
#include <hip/hip_runtime.h>

#define N_NODES   100000
#define N_EDGES   3200000
#define N_FEAT    128
#define HIDDEN    16
#define MLP_H     100
#define N_CLASSES 12
#define N_GRAPHS  512
#define NBLK      391            // ceil(N_NODES/256)
#define BNODES    512            // nodes per bucket (dst>>9)
#define NBUCK     196            // ceil(N_NODES/512)
#define CPAD      16             // counter padding (ints) -> 1 counter / 64B
#define RING      64             // LDS ring slots per bucket in kBin

// ---- bucket histogram (LDS-staged): bcnt[d>>9] += ... ---------------------
__global__ __launch_bounds__(256) void kBCnt(const int* __restrict__ dst,
                                             int* __restrict__ bcnt) {
    __shared__ int h[NBUCK];
    int t = threadIdx.x;
    for (int i = t; i < NBUCK; i += 256) h[i] = 0;
    __syncthreads();
    int nquad = N_EDGES / 4;
    for (int i = blockIdx.x * 256 + t; i < nquad; i += gridDim.x * 256) {
        int4 d4 = ((const int4*)dst)[i];
        atomicAdd(&h[d4.x >> 9], 1);
        atomicAdd(&h[d4.y >> 9], 1);
        atomicAdd(&h[d4.z >> 9], 1);
        atomicAdd(&h[d4.w >> 9], 1);
    }
    __syncthreads();
    for (int i = t; i < NBUCK; i += 256)
        if (h[i]) atomicAdd(&bcnt[i * CPAD], h[i]);
}

// ---- scan: true bases tb[], 16-aligned padded bases pb[] -> gcursor -------
__global__ __launch_bounds__(256) void kBScan(const int* __restrict__ bcnt,
                                              int* __restrict__ tb,
                                              int* __restrict__ pb,
                                              int* __restrict__ gcursor,
                                              int* __restrict__ off) {
    __shared__ int s1[256], s2[256];
    int t = threadIdx.x;
    int c  = (t < NBUCK) ? bcnt[t * CPAD] : 0;
    int ca = (c + 15) & ~15;
    s1[t] = c; s2[t] = ca;
    __syncthreads();
    for (int s = 1; s < 256; s <<= 1) {
        int a1 = (t >= s) ? s1[t - s] : 0;
        int a2 = (t >= s) ? s2[t - s] : 0;
        __syncthreads();
        s1[t] += a1; s2[t] += a2;
        __syncthreads();
    }
    if (t < NBUCK) {
        tb[t] = s1[t] - c;
        int p = s2[t] - ca;
        pb[t] = p;
        gcursor[t * CPAD] = p;
    }
    if (t == 0) { tb[NBUCK] = N_EDGES; off[N_NODES] = N_EDGES; }
}

// ---- LDS-staged binning: 64B single-writer chunk flushes ------------------
__global__ __launch_bounds__(512) void kBin(const int* __restrict__ src,
                                            const int* __restrict__ dst,
                                            int* __restrict__ gcursor,
                                            int* __restrict__ pairs) {
    __shared__ int ring[NBUCK * RING];   // 50176 B
    __shared__ int cnt[NBUCK];
    __shared__ int fl[NBUCK];
    int t = threadIdx.x;
    for (int i = t; i < NBUCK; i += 512) { cnt[i] = 0; fl[i] = 0; }
    __syncthreads();
    const int batch = 512 * 4;                       // 2048 edges per block-iter
    for (int base = blockIdx.x * batch; base < N_EDGES;
         base += gridDim.x * batch) {
        int e0 = base + t * 4;
        if (e0 < N_EDGES) {                          // N_EDGES % 4 == 0
            int4 d4 = *(const int4*)&dst[e0];
            int4 s4 = *(const int4*)&src[e0];
            int dd[4] = {d4.x, d4.y, d4.z, d4.w};
            int ss[4] = {s4.x, s4.y, s4.z, s4.w};
#pragma unroll
            for (int k = 0; k < 4; ++k) {
                int b = dd[k] >> 9;
                int p = atomicAdd(&cnt[b], 1);
                ring[b * RING + (p & (RING - 1))] = (ss[k] << 9) | (dd[k] & 511);
            }
        }
        __syncthreads();
        if (t < NBUCK) {
            while (cnt[t] - fl[t] >= 16) {
                int start = fl[t];
                int gpos = atomicAdd(&gcursor[t * CPAD], 16);
                int rbase = t * RING + (start & (RING - 1)); // 16-aligned, no wrap
                const int4* rp = (const int4*)&ring[rbase];
                int4* gp = (int4*)&pairs[gpos];              // gpos % 16 == 0
                gp[0] = rp[0]; gp[1] = rp[1]; gp[2] = rp[2]; gp[3] = rp[3];
                fl[t] = start + 16;
            }
        }
        __syncthreads();
    }
    if (t < NBUCK) {
        int pending = cnt[t] - fl[t];
        if (pending > 0) {
            int gpos = atomicAdd(&gcursor[t * CPAD], pending);
            for (int k = 0; k < pending; ++k)
                pairs[gpos + k] = ring[t * RING + ((fl[t] + k) & (RING - 1))];
        }
    }
}

// ---- per-bucket: LDS hist -> off/dinv, scatter csr (contiguous window) ----
__global__ __launch_bounds__(512) void kBuild(const int* __restrict__ pairs,
                                              const int* __restrict__ tb,
                                              const int* __restrict__ pb,
                                              int* __restrict__ off,
                                              float* __restrict__ dinv,
                                              int* __restrict__ csr) {
    __shared__ int hist[BNODES];
    __shared__ int sc[BNODES];
    __shared__ int lcur[BNODES];
    int b = blockIdx.x, t = threadIdx.x;
    int ebeg = tb[b];
    int ecnt = tb[b + 1] - ebeg;
    int pbeg = pb[b];
    hist[t] = 0;
    __syncthreads();
    for (int i = t; i < ecnt; i += 512)
        atomicAdd(&hist[pairs[pbeg + i] & 511], 1);
    __syncthreads();
    sc[t] = hist[t];
    __syncthreads();
    for (int s = 1; s < 512; s <<= 1) {
        int a = (t >= s) ? sc[t - s] : 0;
        __syncthreads();
        sc[t] += a;
        __syncthreads();
    }
    int g = b * BNODES + t;
    int excl = ebeg + sc[t] - hist[t];
    lcur[t] = excl;
    if (g < N_NODES) {
        off[g] = excl;
        dinv[g] = rsqrtf((float)hist[t] + 1.0f);  // +1 = self loop
    }
    __syncthreads();
    for (int i = t; i < ecnt; i += 512) {
        int v = pairs[pbeg + i];
        int pos = atomicAdd(&lcur[v & 511], 1);
        csr[pos] = v >> 9;
    }
}

// ---------------- hp = (x @ W1) * dinv[n]  ---------------------------------
__global__ __launch_bounds__(256) void kGemm1(const float* __restrict__ x,
                                              const float* __restrict__ W1,
                                              const float* __restrict__ dinv,
                                              float* __restrict__ hp) {
    __shared__ float Ws[N_FEAT * HIDDEN];  // 8 KB
    for (int t = threadIdx.x; t < N_FEAT * HIDDEN; t += 256) Ws[t] = W1[t];
    __syncthreads();
    int n = blockIdx.x * 256 + threadIdx.x;
    if (n >= N_NODES) return;

    float acc[HIDDEN];
#pragma unroll
    for (int j = 0; j < HIDDEN; ++j) acc[j] = 0.f;

    const float4* xr = (const float4*)(x + (size_t)n * N_FEAT);
#pragma unroll 4
    for (int k4 = 0; k4 < N_FEAT / 4; ++k4) {
        float4 v = xr[k4];
        float xk[4] = {v.x, v.y, v.z, v.w};
#pragma unroll
        for (int kk = 0; kk < 4; ++kk) {
            const float4* wrow = (const float4*)&Ws[(k4 * 4 + kk) * HIDDEN];
#pragma unroll
            for (int j4 = 0; j4 < 4; ++j4) {
                float4 wv = wrow[j4];
                acc[j4 * 4 + 0] += xk[kk] * wv.x;
                acc[j4 * 4 + 1] += xk[kk] * wv.y;
                acc[j4 * 4 + 2] += xk[kk] * wv.z;
                acc[j4 * 4 + 3] += xk[kk] * wv.w;
            }
        }
    }
    float dv = dinv[n];
    float4* hr = (float4*)(hp + (size_t)n * HIDDEN);
#pragma unroll
    for (int j4 = 0; j4 < 4; ++j4)
        hr[j4] = make_float4(acc[j4 * 4 + 0] * dv, acc[j4 * 4 + 1] * dv,
                             acc[j4 * 4 + 2] * dv, acc[j4 * 4 + 3] * dv);
}

// ---- CSR gather-aggregate, prefetched + batched loads ---------------------
// aggval_j = (hp[n][j] + sum_s hp[s][j]) * dinv[n]
// MODE 1: out = dinv[n] * sum_k relu(aggval_k + b1[k]) * W2[k][j]   (layer2 fused)
// MODE 0: out = relu(aggval_j + b2[j])                              (pool input)
template <int MODE>
__global__ __launch_bounds__(256) void kAgg(const float* __restrict__ hp,
                                            const float* __restrict__ dinv,
                                            const int* __restrict__ off,
                                            const int* __restrict__ csr,
                                            const float* __restrict__ W2,
                                            const float* __restrict__ bias,
                                            float* __restrict__ outbuf) {
    __shared__ float W2s[HIDDEN * HIDDEN];
    __shared__ float bs[HIDDEN];
    if (MODE == 1) {
        if (threadIdx.x < HIDDEN * HIDDEN) W2s[threadIdx.x] = W2[threadIdx.x];
    }
    if (threadIdx.x < HIDDEN) bs[threadIdx.x] = bias[threadIdx.x];
    __syncthreads();

    int gid = blockIdx.x * 256 + threadIdx.x;
    int n = gid >> 4;
    int j = gid & 15;
    if (n >= N_NODES) return;

    int beg = off[n], end = off[n + 1];
    float acc = hp[(size_t)n * HIDDEN + j];  // self loop
    int pv = (beg + j < end) ? csr[beg + j] : -1;
    for (int cur = beg; cur < end; cur += 16) {
        int nxt = cur + 16;
        int pn = (nxt + j < end) ? csr[nxt + j] : -1;  // prefetch next batch
        int s[16];
#pragma unroll
        for (int k = 0; k < 16; ++k) s[k] = __shfl(pv, k, 16);
        float f[16];
#pragma unroll
        for (int k = 0; k < 16; ++k)
            f[k] = (s[k] >= 0) ? hp[(size_t)s[k] * HIDDEN + j] : 0.f;
#pragma unroll
        for (int k = 0; k < 16; ++k) acc += f[k];
        pv = pn;
    }
    float dv = dinv[n];
    if (MODE == 1) {
        float t = fmaxf(acc * dv + bs[j], 0.f);
        float o = 0.f;
#pragma unroll
        for (int k = 0; k < 16; ++k)
            o += __shfl(t, k, 16) * W2s[k * HIDDEN + j];
        outbuf[(size_t)n * HIDDEN + j] = o * dv;
    } else {
        outbuf[(size_t)n * HIDDEN + j] = fmaxf(acc * dv + bs[j], 0.f);
    }
}

// ------- pooled[batch[n]] += v[n]  (v already relu(+bias)) -----------------
__global__ __launch_bounds__(256) void kPool(const float* __restrict__ v,
                                             const int* __restrict__ batch,
                                             float* __restrict__ pooled) {
    __shared__ float red[256];
    __shared__ int sseg[2];
    int t = threadIdx.x;
    int ln = t >> 4, j = t & 15;
    int n0 = blockIdx.x * 16;
    int n = n0 + ln;
    if (t == 0) sseg[0] = batch[n0];
    if (t == 1) sseg[1] = batch[min(n0 + 15, N_NODES - 1)];
    float val = 0.f;
    int bg = 0;
    bool valid = (n < N_NODES);
    if (valid) {
        bg = batch[n];
        val = v[(size_t)n * HIDDEN + j];
    }
    __syncthreads();
    if (sseg[0] == sseg[1]) {          // whole block in one graph (common)
        red[t] = val;
        __syncthreads();
        if (ln < 8) red[t] += red[t + 128];
        __syncthreads();
        if (ln < 4) red[t] += red[t + 64];
        __syncthreads();
        if (ln < 2) red[t] += red[t + 32];
        __syncthreads();
        if (ln == 0)
            unsafeAtomicAdd(&pooled[(size_t)sseg[0] * HIDDEN + j],
                            red[t] + red[t + 16]);
    } else {
        if (valid) unsafeAtomicAdd(&pooled[(size_t)bg * HIDDEN + j], val);
    }
}

// ------- g=relu(pooled); g1=relu(g@lw1+lb1); out=g1@lw2+lb2 ----------------
__global__ __launch_bounds__(64) void kMlp(const float* __restrict__ pooled,
                                           const float* __restrict__ lw1,
                                           const float* __restrict__ lb1,
                                           const float* __restrict__ lw2,
                                           const float* __restrict__ lb2,
                                           float* __restrict__ out) {
    int g = blockIdx.x * 64 + threadIdx.x;
    if (g >= N_GRAPHS) return;
    float gv[HIDDEN];
#pragma unroll
    for (int k = 0; k < HIDDEN; ++k)
        gv[k] = fmaxf(pooled[(size_t)g * HIDDEN + k], 0.f);
    float o[N_CLASSES];
#pragma unroll
    for (int c = 0; c < N_CLASSES; ++c) o[c] = lb2[c];
    for (int j = 0; j < MLP_H; ++j) {
        float s = lb1[j];
#pragma unroll
        for (int k = 0; k < HIDDEN; ++k) s += gv[k] * lw1[k * MLP_H + j];
        s = fmaxf(s, 0.f);
#pragma unroll
        for (int c = 0; c < N_CLASSES; ++c) o[c] += s * lw2[j * N_CLASSES + c];
    }
#pragma unroll
    for (int c = 0; c < N_CLASSES; ++c) out[(size_t)g * N_CLASSES + c] = o[c];
}

extern "C" void kernel_launch(void* const* d_in, const int* in_sizes, int n_in,
                              void* d_out, int out_size, void* d_ws,
                              size_t ws_size, hipStream_t stream) {
    const float* x     = (const float*)d_in[0];
    const int*   ei    = (const int*)d_in[1];
    const int*   batch = (const int*)d_in[2];
    const float* W1    = (const float*)d_in[3];
    const float* b1    = (const float*)d_in[4];
    const float* W2    = (const float*)d_in[5];
    const float* b2    = (const float*)d_in[6];
    const float* lw1   = (const float*)d_in[7];
    const float* lb1   = (const float*)d_in[8];
    const float* lw2   = (const float*)d_in[9];
    const float* lb2   = (const float*)d_in[10];
    float* out = (float*)d_out;

    const int* src = ei;
    const int* dst = ei + N_EDGES;

    // workspace layout (bytes)
    char* ws = (char*)d_ws;
    int*   bcnt    = (int*)(ws + 0);         // 196*64 = 12544 -> 16384
    int*   gcursor = (int*)(ws + 16384);     // 12544
    int*   tb      = (int*)(ws + 32768);     // 788
    int*   pb      = (int*)(ws + 36864);     // 788
    float* dinv    = (float*)(ws + 40960);   // 400000
    int*   off     = (int*)(ws + 442368);    // 400004
    int*   pairs   = (int*)(ws + 843776);    // 12812544 (dead after kBuild)
    float* hp      = (float*)(ws + 843776);  //  6400000 (overlays pairs; layer1 hp, then pool input)
    float* hp2     = (float*)(ws + 7243776); //  6400000 (overlays pairs)
    int*   csr     = (int*)(ws + 13656576);  // 12800000
    float* pooled  = (float*)(ws + 26456576);//    32768

    hipMemsetAsync(bcnt, 0, NBUCK * CPAD * 4, stream);
    hipMemsetAsync(pooled, 0, 32768, stream);

    kBCnt<<<256, 256, 0, stream>>>(dst, bcnt);
    kBScan<<<1, 256, 0, stream>>>(bcnt, tb, pb, gcursor, off);
    kBin<<<128, 512, 0, stream>>>(src, dst, gcursor, pairs);
    kBuild<<<NBUCK, 512, 0, stream>>>(pairs, tb, pb, off, dinv, csr);

    kGemm1<<<NBLK, 256, 0, stream>>>(x, W1, dinv, hp);
    // layer1 aggregate + layer2 transform fused -> hp2
    kAgg<1><<<(N_NODES * HIDDEN) / 256, 256, 0, stream>>>(hp, dinv, off, csr,
                                                          W2, b1, hp2);
    // layer2 aggregate + relu(+b2) -> hp (reused as pool input)
    kAgg<0><<<(N_NODES * HIDDEN) / 256, 256, 0, stream>>>(hp2, dinv, off, csr,
                                                          W2, b2, hp);
    kPool<<<(N_NODES + 15) / 16, 256, 0, stream>>>(hp, batch, pooled);
    kMlp<<<(N_GRAPHS + 63) / 64, 64, 0, stream>>>(pooled, lw1, lb1, lw2, lb2, out);
}